// Round 4
// baseline (14468.776 us; speedup 1.0000x reference)
//
#include <hip/hip_runtime.h>

// Trajectron sliding-window LSTM embed:
//   inputs [T=256, B=128, N=4, D=2] f32
//   his LSTM H=32 over n=3; int LSTM H=8 over n=0; window 64 ending at t
//   out[t,b,:] = [h_his | h_int] @ W_out.T + b_out   -> [256,128,2] f32
//
// Round-4 mapping: chain-per-lane-pair. lane = p*32 + bl owns chain (t, b0+bl)
// gate-half p (p0: i,f rows; p1: g,o rows). h[32], c[32] mirrored in VGPRs on
// both halves -> dot products are pure register pk_fma (no broadcast at all).
// Weights streamed per gate-unit j from L1 (2-way-uniform addresses,
// double-buffered, immediate-offset addressing). 2 shfl_xor(32) per j swap
// the gate pairs. 1024 single-wave blocks = 1 wave per SIMD, whole machine.
// Each wave then runs the tiny int LSTM for the same 32 chains and writes
// the final projection alone: no LDS, no barriers, no atomics.

typedef float v2f __attribute__((ext_vector_type(2)));

static __device__ __forceinline__ float fexp2(float x) {
    return __builtin_amdgcn_exp2f(x);
}
static __device__ __forceinline__ float frcp(float x) {
    return __builtin_amdgcn_rcpf(x);
}
// sigmoid(x) = 1/(1+2^(-x*log2e)); saturates cleanly to 0/1
static __device__ __forceinline__ float fsig(float x) {
    return frcp(1.f + fexp2(-1.44269504f * x));
}
// tanh(x) = 1 - 2/(1+2^(2x*log2e)); saturates cleanly to +/-1
static __device__ __forceinline__ float ftanh_(float x) {
    return fmaf(-2.f, frcp(1.f + fexp2(2.88539008f * x)), 1.f);
}

__global__ __launch_bounds__(64, 1) void traj_kernel(
    const float* __restrict__ inp,       // [256][128][4][2]
    const float* __restrict__ Wih_his,   // [128][2]
    const float* __restrict__ Whh_his,   // [128][32]
    const float* __restrict__ bih_his,   // [128]
    const float* __restrict__ bhh_his,   // [128]
    const float* __restrict__ Wih_int,   // [32][2]
    const float* __restrict__ Whh_int,   // [32][8]
    const float* __restrict__ bih_int,   // [32]
    const float* __restrict__ bhh_int,   // [32]
    const float* __restrict__ W_out,     // [2][40]
    const float* __restrict__ b_out,     // [2]
    float* __restrict__ out)             // [256][128][2]
{
    const int lane = threadIdx.x;
    const int p    = lane >> 5;          // gate-half
    const int bl   = lane & 31;          // chain within wave
    const int bid  = blockIdx.x;
    const int t    = bid & 255;          // swizzle: consecutive bids -> diff t
    const int b    = ((bid >> 8) << 5) + bl;
    const int nsteps = (t >= 63) ? 64 : (t + 1);
    const int tau0   = (t >= 63) ? (t - 63) : 0;

    const float sclA = p ? 2.f : 1.f;    // tanh(a)=2*sig(2a)-1 on p=1
    const float offA = p ? -1.f : 0.f;

    // ================= HIS LSTM: H = 32 =================
    v2f   h2[16];                         // mirrored hidden state (k-pairs)
    float c[32];
#pragma unroll
    for (int m = 0; m < 16; ++m) h2[m] = (v2f){0.f, 0.f};
#pragma unroll
    for (int j = 0; j < 32; ++j) c[j] = 0.f;

    {
        const int rbase = p * 64;        // rows: p0 -> i(0..31),f(32..63); p1 -> g,o
        const float4* pa4 = reinterpret_cast<const float4*>(Whh_his + rbase * 32);
        const float4* pb4 = reinterpret_cast<const float4*>(Whh_his + (rbase + 32) * 32);
        const float*  pbihA = bih_his + rbase;
        const float*  pbhhA = bhh_his + rbase;
        const float*  pbihB = bih_his + rbase + 32;
        const float*  pbhhB = bhh_his + rbase + 32;
        const v2f*    pwihA = reinterpret_cast<const v2f*>(Wih_his) + rbase;
        const v2f*    pwihB = pwihA + 32;

        const float* xq = inp + tau0 * 1024 + b * 8 + 6;   // n=3
        float x0 = xq[0], x1 = xq[1];
        xq += 1024;

        float4 wA[2][8], wB[2][8];
        v2f    bb[2][2], wx[2][2];

        // preload j=0 into slot 0
#pragma unroll
        for (int q = 0; q < 8; ++q) { wA[0][q] = pa4[q]; wB[0][q] = pb4[q]; }
        bb[0][0] = (v2f){pbihA[0], pbhhA[0]};
        bb[0][1] = (v2f){pbihB[0], pbhhB[0]};
        wx[0][0] = pwihA[0];
        wx[0][1] = pwihB[0];

#pragma unroll 1
        for (int s = 0; s < nsteps; ++s) {
            float nx0 = 0.f, nx1 = 0.f;
            if (s + 1 < nsteps) { nx0 = xq[0]; nx1 = xq[1]; }   // uniform branch
            xq += 1024;
            const v2f xv = {x0, x1};

            v2f hn2[16];
#pragma unroll
            for (int j = 0; j < 32; ++j) {
                const int cur = j & 1, nxt = cur ^ 1;
                if (j < 31) {                       // prefetch j+1
#pragma unroll
                    for (int q = 0; q < 8; ++q) {
                        wA[nxt][q] = pa4[(j + 1) * 8 + q];
                        wB[nxt][q] = pb4[(j + 1) * 8 + q];
                    }
                    bb[nxt][0] = (v2f){pbihA[j + 1], pbhhA[j + 1]};
                    bb[nxt][1] = (v2f){pbihB[j + 1], pbhhB[j + 1]};
                    wx[nxt][0] = pwihA[j + 1];
                    wx[nxt][1] = pwihB[j + 1];
                } else {                            // reload j=0 for next step
#pragma unroll
                    for (int q = 0; q < 8; ++q) {
                        wA[nxt][q] = pa4[q];
                        wB[nxt][q] = pb4[q];
                    }
                    bb[nxt][0] = (v2f){pbihA[0], pbhhA[0]};
                    bb[nxt][1] = (v2f){pbihB[0], pbhhB[0]};
                    wx[nxt][0] = pwihA[0];
                    wx[nxt][1] = pwihB[0];
                }

                v2f accA = bb[cur][0];              // (bih, bhh): summed by
                v2f accB = bb[cur][1];              // the horizontal add below
                accA += wx[cur][0] * xv;            // v_pk_fma_f32
                accB += wx[cur][1] * xv;
#pragma unroll
                for (int q = 0; q < 8; ++q) {
                    const float4 a = wA[cur][q];
                    const float4 w = wB[cur][q];
                    accA += (v2f){a.x, a.y} * h2[2 * q];
                    accA += (v2f){a.z, a.w} * h2[2 * q + 1];
                    accB += (v2f){w.x, w.y} * h2[2 * q];
                    accB += (v2f){w.z, w.w} * h2[2 * q + 1];
                }
                const float aA = accA.x + accA.y;
                const float aB = accB.x + accB.y;

                const float vA = fmaf(sclA, fsig(sclA * aA), offA); // p0:sig(i) p1:tanh(g)
                const float vB = fsig(aB);                          // p0:sig(f) p1:sig(o)
                const float oA = __shfl_xor(vA, 32);
                const float oB = __shfl_xor(vB, 32);

                const float gi = p ? oA : vA;
                const float gf = p ? oB : vB;
                const float gg = p ? vA : oA;
                const float go = p ? vB : oB;

                const float cn = fmaf(gf, c[j], gi * gg);
                c[j] = cn;
                const float hj = go * ftanh_(cn);
                if (j & 1) hn2[j >> 1].y = hj; else hn2[j >> 1].x = hj;
            }
#pragma unroll
            for (int m = 0; m < 16; ++m) h2[m] = hn2[m];   // publish new h
            x0 = nx0; x1 = nx1;
        }
    }

    // ================= INT LSTM: H = 8 =================
    v2f   hi2[4];
    float ci[8];
#pragma unroll
    for (int m = 0; m < 4; ++m) hi2[m] = (v2f){0.f, 0.f};
#pragma unroll
    for (int j = 0; j < 8; ++j) ci[j] = 0.f;

    {
        const int rbase = p * 16;        // p0: i(0..7),f(8..15); p1: g,o
        const float4* pa4 = reinterpret_cast<const float4*>(Whh_int + rbase * 8);
        const float4* pb4 = reinterpret_cast<const float4*>(Whh_int + (rbase + 8) * 8);
        const float*  pbihA = bih_int + rbase;
        const float*  pbhhA = bhh_int + rbase;
        const float*  pbihB = bih_int + rbase + 8;
        const float*  pbhhB = bhh_int + rbase + 8;
        const v2f*    pwihA = reinterpret_cast<const v2f*>(Wih_int) + rbase;
        const v2f*    pwihB = pwihA + 8;

        const float* xq = inp + tau0 * 1024 + b * 8;       // n=0
        float x0 = xq[0], x1 = xq[1];
        xq += 1024;

#pragma unroll 1
        for (int s = 0; s < nsteps; ++s) {
            float nx0 = 0.f, nx1 = 0.f;
            if (s + 1 < nsteps) { nx0 = xq[0]; nx1 = xq[1]; }
            xq += 1024;
            const v2f xv = {x0, x1};

            v2f hn2[4];
#pragma unroll
            for (int j = 0; j < 8; ++j) {
                v2f accA = (v2f){pbihA[j], pbhhA[j]};
                v2f accB = (v2f){pbihB[j], pbhhB[j]};
                accA += pwihA[j] * xv;
                accB += pwihB[j] * xv;
#pragma unroll
                for (int q = 0; q < 2; ++q) {
                    const float4 a = pa4[j * 2 + q];
                    const float4 w = pb4[j * 2 + q];
                    accA += (v2f){a.x, a.y} * hi2[2 * q];
                    accA += (v2f){a.z, a.w} * hi2[2 * q + 1];
                    accB += (v2f){w.x, w.y} * hi2[2 * q];
                    accB += (v2f){w.z, w.w} * hi2[2 * q + 1];
                }
                const float aA = accA.x + accA.y;
                const float aB = accB.x + accB.y;

                const float vA = fmaf(sclA, fsig(sclA * aA), offA);
                const float vB = fsig(aB);
                const float oA = __shfl_xor(vA, 32);
                const float oB = __shfl_xor(vB, 32);

                const float gi = p ? oA : vA;
                const float gf = p ? oB : vB;
                const float gg = p ? vA : oA;
                const float go = p ? vB : oB;

                const float cn = fmaf(gf, ci[j], gi * gg);
                ci[j] = cn;
                const float hj = go * ftanh_(cn);
                if (j & 1) hn2[j >> 1].y = hj; else hn2[j >> 1].x = hj;
            }
#pragma unroll
            for (int m = 0; m < 4; ++m) hi2[m] = hn2[m];
            x0 = nx0; x1 = nx1;
        }
    }

    // ================= projection =================
    float e0 = b_out[0], e1 = b_out[1];
#pragma unroll
    for (int j = 0; j < 32; ++j) {
        const float hj = (j & 1) ? h2[j >> 1].y : h2[j >> 1].x;
        e0 = fmaf(W_out[j], hj, e0);
        e1 = fmaf(W_out[40 + j], hj, e1);
    }
#pragma unroll
    for (int j = 0; j < 8; ++j) {
        const float hj = (j & 1) ? hi2[j >> 1].y : hi2[j >> 1].x;
        e0 = fmaf(W_out[32 + j], hj, e0);
        e1 = fmaf(W_out[72 + j], hj, e1);
    }
    if (p == 0) {
        float2 o; o.x = e0; o.y = e1;
        reinterpret_cast<float2*>(out)[t * 128 + b] = o;
    }
}

extern "C" void kernel_launch(void* const* d_in, const int* in_sizes, int n_in,
                              void* d_out, int out_size, void* d_ws, size_t ws_size,
                              hipStream_t stream) {
    const float* inp     = (const float*)d_in[0];
    const float* Wih_his = (const float*)d_in[1];
    const float* Whh_his = (const float*)d_in[2];
    const float* bih_his = (const float*)d_in[3];
    const float* bhh_his = (const float*)d_in[4];
    const float* Wih_int = (const float*)d_in[5];
    const float* Whh_int = (const float*)d_in[6];
    const float* bih_int = (const float*)d_in[7];
    const float* bhh_int = (const float*)d_in[8];
    const float* W_out   = (const float*)d_in[9];
    const float* b_out   = (const float*)d_in[10];
    float* out = (float*)d_out;

    // 1024 blocks x 64 threads: 32 chains per wave, 1 wave per SIMD machine-wide
    traj_kernel<<<dim3(1024), dim3(64), 0, stream>>>(
        inp, Wih_his, Whh_his, bih_his, bhh_his,
        Wih_int, Whh_int, bih_int, bhh_int, W_out, b_out, out);
}

// Round 5
// 1830.214 us; speedup vs baseline: 7.9055x; 7.9055x over previous
//
#include <hip/hip_runtime.h>

// Trajectron sliding-window LSTM embed:
//   inputs [T=256, B=128, N=4, D=2] f32
//   his LSTM H=32 over n=3; int LSTM H=8 over n=0; window 64 ending at t
//   out[t,b,:] = [h_his | h_int] @ W_out.T + b_out   -> [256,128,2] f32
//
// Round-5 mapping: PURE chain-per-lane. Lane owns a full chain: h[32], c[32]
// in VGPRs; weights are IDENTICAL across lanes per instruction -> streamed
// through the SCALAR pipe (s_load -> SGPR) and consumed as the scalar operand
// of v_pk_fma_f32. Zero VGPR cost for weights (round-4's spill disaster:
// VGPR=256, 14 GB HBM spill traffic), zero cross-lane ops, zero LDS, zero
// barriers. 512 blocks x 64 threads = 64 chains/wave, uniform t per wave.
// A pre-pass kernel folds -log2e / -2log2e into weights+bias in d_ws so
// sigmoid = rcp(1+exp2(a)) with no per-gate scaling multiply.

typedef float v2f __attribute__((ext_vector_type(2)));

static __device__ __forceinline__ float fexp2(float x) {
    return __builtin_amdgcn_exp2f(x);
}
static __device__ __forceinline__ float frcp(float x) {
    return __builtin_amdgcn_rcpf(x);
}

#define LOG2E    1.442695041f
#define TWOLOG2E 2.885390082f

// ws layout (floats):
//   [0,256)     hisX : 2*r+{0,1} = Wih_his[r][:] * s_r
//   [256,384)   hisB : (bih+bhh)[r] * s_r
//   [384,4480)  hisW : r*32+k = Whh_his[r][k] * s_r
//   [4480,4544) intX
//   [4544,4576) intB
//   [4576,4832) intW : r*8+k
// s_r = -log2e for sigmoid rows (i,f,o), -2*log2e for g rows.
__global__ __launch_bounds__(256) void prep_kernel(
    const float* __restrict__ Wih_his, const float* __restrict__ Whh_his,
    const float* __restrict__ bih_his, const float* __restrict__ bhh_his,
    const float* __restrict__ Wih_int, const float* __restrict__ Whh_int,
    const float* __restrict__ bih_int, const float* __restrict__ bhh_int,
    float* __restrict__ ws)
{
    const int i = blockIdx.x * 256 + threadIdx.x;
    if (i < 256) {                      // hisX
        const int r = i >> 1;
        const float s = (r >= 64 && r < 96) ? -TWOLOG2E : -LOG2E;
        ws[i] = Wih_his[i] * s;
    } else if (i < 384) {               // hisB
        const int r = i - 256;
        const float s = (r >= 64 && r < 96) ? -TWOLOG2E : -LOG2E;
        ws[i] = (bih_his[r] + bhh_his[r]) * s;
    } else if (i < 4480) {              // hisW
        const int e = i - 384, r = e >> 5;
        const float s = (r >= 64 && r < 96) ? -TWOLOG2E : -LOG2E;
        ws[i] = Whh_his[e] * s;
    } else if (i < 4544) {              // intX
        const int e = i - 4480, r = e >> 1;
        const float s = (r >= 16 && r < 24) ? -TWOLOG2E : -LOG2E;
        ws[i] = Wih_int[e] * s;
    } else if (i < 4576) {              // intB
        const int r = i - 4544;
        const float s = (r >= 16 && r < 24) ? -TWOLOG2E : -LOG2E;
        ws[i] = (bih_int[r] + bhh_int[r]) * s;
    } else if (i < 4832) {              // intW
        const int e = i - 4576, r = e >> 3;
        const float s = (r >= 16 && r < 24) ? -TWOLOG2E : -LOG2E;
        ws[i] = Whh_int[e] * s;
    }
}

__global__ __launch_bounds__(64) void traj_kernel(
    const float* __restrict__ inp,     // [256][128][4][2]
    const float* __restrict__ ws,      // preprocessed weights (see prep)
    const float* __restrict__ W_out,   // [2][40]
    const float* __restrict__ b_out,   // [2]
    float* __restrict__ out)           // [256][128][2]
{
    const int lane = threadIdx.x;
    const int bid  = blockIdx.x;
    const int t    = bid >> 1;                     // uniform per wave
    const int b    = ((bid & 1) << 6) | lane;      // chain = (t, b)
    const int nsteps = (t >= 63) ? 64 : (t + 1);
    const int tau0   = (t >= 63) ? (t - 63) : 0;

    const v2f*   wsX = reinterpret_cast<const v2f*>(ws);        // per-row (w0,w1)
    const float* wsB = ws + 256;
    const float* wsW = ws + 384;

    // ================= HIS LSTM: H = 32 =================
    v2f   h2[16];
    float c[32];
#pragma unroll
    for (int m = 0; m < 16; ++m) h2[m] = (v2f){0.f, 0.f};
#pragma unroll
    for (int j = 0; j < 32; ++j) c[j] = 0.f;

    {
        const float* xq = inp + tau0 * 1024 + b * 8 + 6;   // n=3
        float x0 = xq[0], x1 = xq[1];
        xq += 1024;

#pragma unroll 1
        for (int s = 0; s < nsteps; ++s) {
            float nx0 = 0.f, nx1 = 0.f;
            if (s + 1 < nsteps) { nx0 = xq[0]; nx1 = xq[1]; }  // uniform branch
            xq += 1024;
            const v2f xv = {x0, x1};

            float hn[32];
#pragma unroll
            for (int j = 0; j < 32; ++j) {
                // 4 gate rows: i=j, f=32+j, g=64+j, o=96+j (all lane-uniform
                // weights -> SGPR operands; 4 independent acc chains for ILP)
                v2f a0 = wsX[j]      * xv;
                v2f a1 = wsX[32 + j] * xv;
                v2f a2 = wsX[64 + j] * xv;
                v2f a3 = wsX[96 + j] * xv;
                const v2f* w0 = reinterpret_cast<const v2f*>(wsW + j * 32);
                const v2f* w1 = reinterpret_cast<const v2f*>(wsW + (32 + j) * 32);
                const v2f* w2 = reinterpret_cast<const v2f*>(wsW + (64 + j) * 32);
                const v2f* w3 = reinterpret_cast<const v2f*>(wsW + (96 + j) * 32);
#pragma unroll
                for (int k = 0; k < 16; ++k) {
                    const v2f hk = h2[k];
                    a0 += w0[k] * hk;        // v_pk_fma_f32 vD, s[pair], vH, vD
                    a1 += w1[k] * hk;
                    a2 += w2[k] * hk;
                    a3 += w3[k] * hk;
                }
                const float ai = a0.x + a0.y + wsB[j];
                const float af = a1.x + a1.y + wsB[32 + j];
                const float ag = a2.x + a2.y + wsB[64 + j];
                const float ao = a3.x + a3.y + wsB[96 + j];

                // pre-scaled: a = -log2e*orig (i,f,o) / -2log2e*orig (g)
                const float si = frcp(1.f + fexp2(ai));
                const float sf = frcp(1.f + fexp2(af));
                const float tg = fmaf(2.f, frcp(1.f + fexp2(ag)), -1.f);
                const float so = frcp(1.f + fexp2(ao));

                const float cn = fmaf(sf, c[j], si * tg);
                c[j] = cn;
                const float th = fmaf(-2.f, frcp(1.f + fexp2(TWOLOG2E * cn)), 1.f);
                hn[j] = so * th;
            }
#pragma unroll
            for (int m = 0; m < 16; ++m) h2[m] = (v2f){hn[2 * m], hn[2 * m + 1]};
            x0 = nx0; x1 = nx1;
        }
    }

    // ================= INT LSTM: H = 8 =================
    v2f   h2i[4];
    float ci[8];
#pragma unroll
    for (int m = 0; m < 4; ++m) h2i[m] = (v2f){0.f, 0.f};
#pragma unroll
    for (int j = 0; j < 8; ++j) ci[j] = 0.f;

    {
        const v2f*   wsXi = reinterpret_cast<const v2f*>(ws + 4480);
        const float* wsBi = ws + 4544;
        const float* wsWi = ws + 4576;

        const float* xq = inp + tau0 * 1024 + b * 8;       // n=0
        float x0 = xq[0], x1 = xq[1];
        xq += 1024;

#pragma unroll 1
        for (int s = 0; s < nsteps; ++s) {
            float nx0 = 0.f, nx1 = 0.f;
            if (s + 1 < nsteps) { nx0 = xq[0]; nx1 = xq[1]; }
            xq += 1024;
            const v2f xv = {x0, x1};

            float hn[8];
#pragma unroll
            for (int j = 0; j < 8; ++j) {
                v2f a0 = wsXi[j]      * xv;
                v2f a1 = wsXi[8 + j]  * xv;
                v2f a2 = wsXi[16 + j] * xv;
                v2f a3 = wsXi[24 + j] * xv;
                const v2f* w0 = reinterpret_cast<const v2f*>(wsWi + j * 8);
                const v2f* w1 = reinterpret_cast<const v2f*>(wsWi + (8 + j) * 8);
                const v2f* w2 = reinterpret_cast<const v2f*>(wsWi + (16 + j) * 8);
                const v2f* w3 = reinterpret_cast<const v2f*>(wsWi + (24 + j) * 8);
#pragma unroll
                for (int k = 0; k < 4; ++k) {
                    const v2f hk = h2i[k];
                    a0 += w0[k] * hk;
                    a1 += w1[k] * hk;
                    a2 += w2[k] * hk;
                    a3 += w3[k] * hk;
                }
                const float ai = a0.x + a0.y + wsBi[j];
                const float af = a1.x + a1.y + wsBi[8 + j];
                const float ag = a2.x + a2.y + wsBi[16 + j];
                const float ao = a3.x + a3.y + wsBi[24 + j];

                const float si = frcp(1.f + fexp2(ai));
                const float sf = frcp(1.f + fexp2(af));
                const float tg = fmaf(2.f, frcp(1.f + fexp2(ag)), -1.f);
                const float so = frcp(1.f + fexp2(ao));

                const float cn = fmaf(sf, ci[j], si * tg);
                ci[j] = cn;
                const float th = fmaf(-2.f, frcp(1.f + fexp2(TWOLOG2E * cn)), 1.f);
                hn[j] = so * th;
            }
#pragma unroll
            for (int m = 0; m < 4; ++m) h2i[m] = (v2f){hn[2 * m], hn[2 * m + 1]};
            x0 = nx0; x1 = nx1;
        }
    }

    // ================= projection (per lane, no reduction) =================
    float e0 = b_out[0], e1 = b_out[1];
#pragma unroll
    for (int j = 0; j < 32; ++j) {
        const float hj = (j & 1) ? h2[j >> 1].y : h2[j >> 1].x;
        e0 = fmaf(W_out[j], hj, e0);
        e1 = fmaf(W_out[40 + j], hj, e1);
    }
#pragma unroll
    for (int j = 0; j < 8; ++j) {
        const float hj = (j & 1) ? h2i[j >> 1].y : h2i[j >> 1].x;
        e0 = fmaf(W_out[32 + j], hj, e0);
        e1 = fmaf(W_out[72 + j], hj, e1);
    }
    float2 o; o.x = e0; o.y = e1;
    reinterpret_cast<float2*>(out)[t * 128 + b] = o;
}

extern "C" void kernel_launch(void* const* d_in, const int* in_sizes, int n_in,
                              void* d_out, int out_size, void* d_ws, size_t ws_size,
                              hipStream_t stream) {
    const float* inp     = (const float*)d_in[0];
    const float* Wih_his = (const float*)d_in[1];
    const float* Whh_his = (const float*)d_in[2];
    const float* bih_his = (const float*)d_in[3];
    const float* bhh_his = (const float*)d_in[4];
    const float* Wih_int = (const float*)d_in[5];
    const float* Whh_int = (const float*)d_in[6];
    const float* bih_int = (const float*)d_in[7];
    const float* bhh_int = (const float*)d_in[8];
    const float* W_out   = (const float*)d_in[9];
    const float* b_out   = (const float*)d_in[10];
    float* out = (float*)d_out;
    float* ws  = (float*)d_ws;

    // pre-pass: fold log2e scales + bias merge into ws (4832 floats)
    prep_kernel<<<dim3(19), dim3(256), 0, stream>>>(
        Wih_his, Whh_his, bih_his, bhh_his,
        Wih_int, Whh_int, bih_int, bhh_int, ws);

    // 512 blocks x 64 threads: 64 chains per wave, uniform t per wave
    traj_kernel<<<dim3(512), dim3(64), 0, stream>>>(
        inp, ws, W_out, b_out, out);
}

// Round 6
// 559.154 us; speedup vs baseline: 25.8762x; 3.2732x over previous
//
#include <hip/hip_runtime.h>

// Trajectron sliding-window LSTM embed:
//   inputs [T=256, B=128, N=4, D=2] f32
//   his LSTM H=32 over n=3; int LSTM H=8 over n=0; window 64 ending at t
//   out[t,b,:] = [h_his | h_int] @ W_out.T + b_out   -> [256,128,2] f32
//
// Round-6: chain-per-lane compute (pure VGPR pk_fma dot products) + weights
// via LDS UNIFORM-ADDRESS broadcast reads (free, in-order lgkmcnt, deeply
// pipelined -- fixes R5's scalar-pipe OoO drain) + 4-way unit split across
// the block's waves for occupancy (2048 waves = 2/SIMD; fixes R5's 0.5/SIMD).
// Per step: each wave computes 8 his-units + 2 int-units for 64 chains,
// publishes new h (5 x ds_write_b64), ONE __syncthreads (double-buffered,
// single barrier per step is race-free), reads the other 15 pairs back.
// Weight/bias scales (-log2e / -2log2e) folded by the prep pass (R5-verified).

typedef float v2f __attribute__((ext_vector_type(2)));

static __device__ __forceinline__ float fexp2(float x) {
    return __builtin_amdgcn_exp2f(x);
}
static __device__ __forceinline__ float frcp(float x) {
    return __builtin_amdgcn_rcpf(x);
}

#define LOG2E    1.442695041f
#define TWOLOG2E 2.885390082f

// ws layout (floats) -- identical to round 5 (correctness-verified):
//   [0,256)     hisX : 2*r+{0,1} = Wih_his[r][:] * s_r
//   [256,384)   hisB : (bih+bhh)[r] * s_r
//   [384,4480)  hisW : r*32+k = Whh_his[r][k] * s_r
//   [4480,4544) intX
//   [4544,4576) intB
//   [4576,4832) intW : r*8+k
// s_r = -log2e for sigmoid rows (i,f,o), -2*log2e for g rows.
__global__ __launch_bounds__(256) void prep_kernel(
    const float* __restrict__ Wih_his, const float* __restrict__ Whh_his,
    const float* __restrict__ bih_his, const float* __restrict__ bhh_his,
    const float* __restrict__ Wih_int, const float* __restrict__ Whh_int,
    const float* __restrict__ bih_int, const float* __restrict__ bhh_int,
    float* __restrict__ ws)
{
    const int i = blockIdx.x * 256 + threadIdx.x;
    if (i < 256) {                      // hisX
        const int r = i >> 1;
        const float s = (r >= 64 && r < 96) ? -TWOLOG2E : -LOG2E;
        ws[i] = Wih_his[i] * s;
    } else if (i < 384) {               // hisB
        const int r = i - 256;
        const float s = (r >= 64 && r < 96) ? -TWOLOG2E : -LOG2E;
        ws[i] = (bih_his[r] + bhh_his[r]) * s;
    } else if (i < 4480) {              // hisW
        const int e = i - 384, r = e >> 5;
        const float s = (r >= 64 && r < 96) ? -TWOLOG2E : -LOG2E;
        ws[i] = Whh_his[e] * s;
    } else if (i < 4544) {              // intX
        const int e = i - 4480, r = e >> 1;
        const float s = (r >= 16 && r < 24) ? -TWOLOG2E : -LOG2E;
        ws[i] = Wih_int[e] * s;
    } else if (i < 4576) {              // intB
        const int r = i - 4544;
        const float s = (r >= 16 && r < 24) ? -TWOLOG2E : -LOG2E;
        ws[i] = (bih_int[r] + bhh_int[r]) * s;
    } else if (i < 4832) {              // intW
        const int e = i - 4576, r = e >> 3;
        const float s = (r >= 16 && r < 24) ? -TWOLOG2E : -LOG2E;
        ws[i] = Whh_int[e] * s;
    }
}

__global__ __launch_bounds__(256, 2) void traj_kernel(
    const float* __restrict__ inp,     // [256][128][4][2]
    const float* __restrict__ ws,      // preprocessed weights (see prep)
    const float* __restrict__ W_out,   // [2][40]
    const float* __restrict__ b_out,   // [2]
    float* __restrict__ out)           // [256][128][2]
{
    __shared__ __align__(16) float lw[4832];   // broadcast weight copy
    __shared__ float2 hhx[2][16][64];          // his h pairs [buf][pair][chain]
    __shared__ float2 hix[2][4][64];           // int h pairs

    const int tid  = threadIdx.x;
    const int wave = tid >> 6;
    const int lane = tid & 63;
    const int bid  = blockIdx.x;
    const int t    = bid >> 1;                  // uniform per block
    const int b    = ((bid & 1) << 6) | lane;   // this lane's chain is (t,b)
    const int nsteps = (t >= 63) ? 64 : (t + 1);
    const int tau0   = (t >= 63) ? (t - 63) : 0;

    // ---- stage weights global -> LDS (once) ----
    {
        const float4* src = reinterpret_cast<const float4*>(ws);
        float4*       dst = reinterpret_cast<float4*>(lw);
#pragma unroll
        for (int i = 0; i < 5; ++i) {
            const int idx = tid + i * 256;
            if (idx < 1208) dst[idx] = src[idx];
        }
    }
    __syncthreads();

    const int ju0 = wave * 8;    // own his units [ju0, ju0+8)
    const int ji0 = wave * 2;    // own int units [ji0, ji0+2)

    // own biases -> VGPRs (40 regs; saves a ds read per gate per step)
    float bHr[4][8], bIr[4][2];
#pragma unroll
    for (int g = 0; g < 4; ++g) {
#pragma unroll
        for (int jj = 0; jj < 8; ++jj) bHr[g][jj] = lw[256 + g * 32 + ju0 + jj];
#pragma unroll
        for (int jj = 0; jj < 2; ++jj) bIr[g][jj] = lw[4544 + g * 8 + ji0 + jj];
    }

    const v2f*   wX  = reinterpret_cast<const v2f*>(lw);          // [128]
    const float* wW  = lw + 384;                                  // [128][32]
    const v2f*   wXi = reinterpret_cast<const v2f*>(lw + 4480);   // [32]
    const float* wWi = lw + 4576;                                 // [32][8]

    // full h mirrored in regs; c only for own units
    v2f h2[16], hi2[4];
    float c[8], ci[2];
#pragma unroll
    for (int m = 0; m < 16; ++m) h2[m] = (v2f){0.f, 0.f};
#pragma unroll
    for (int m = 0; m < 4; ++m) hi2[m] = (v2f){0.f, 0.f};
#pragma unroll
    for (int m = 0; m < 8; ++m) c[m] = 0.f;
    ci[0] = ci[1] = 0.f;

    const float* xq = inp + tau0 * 1024 + b * 8;
    float2 xi = *reinterpret_cast<const float2*>(xq);       // n=0
    float2 xh = *reinterpret_cast<const float2*>(xq + 6);   // n=3
    xq += 1024;

#pragma unroll 1
    for (int s = 0; s < nsteps; ++s) {
        float2 nxi = {0.f, 0.f}, nxh = {0.f, 0.f};
        if (s + 1 < nsteps) {                               // uniform branch
            nxi = *reinterpret_cast<const float2*>(xq);
            nxh = *reinterpret_cast<const float2*>(xq + 6);
        }
        xq += 1024;
        const v2f xvh = {xh.x, xh.y};
        const v2f xvi = {xi.x, xi.y};

        float hnh[8], hni[2];

        // ---- own 8 his units ----
#pragma unroll
        for (int jj = 0; jj < 8; ++jj) {
            const int ju = ju0 + jj;
            v2f a0 = wX[ju]      * xvh;      // uniform-addr LDS broadcasts
            v2f a1 = wX[32 + ju] * xvh;
            v2f a2 = wX[64 + ju] * xvh;
            v2f a3 = wX[96 + ju] * xvh;
            const v2f* w0 = reinterpret_cast<const v2f*>(wW + ju * 32);
            const v2f* w1 = reinterpret_cast<const v2f*>(wW + (32 + ju) * 32);
            const v2f* w2 = reinterpret_cast<const v2f*>(wW + (64 + ju) * 32);
            const v2f* w3 = reinterpret_cast<const v2f*>(wW + (96 + ju) * 32);
#pragma unroll
            for (int k = 0; k < 16; ++k) {
                const v2f hk = h2[k];
                a0 += w0[k] * hk;            // v_pk_fma_f32, all-VGPR
                a1 += w1[k] * hk;
                a2 += w2[k] * hk;
                a3 += w3[k] * hk;
            }
            const float ai = a0.x + a0.y + bHr[0][jj];
            const float af = a1.x + a1.y + bHr[1][jj];
            const float ag = a2.x + a2.y + bHr[2][jj];
            const float ao = a3.x + a3.y + bHr[3][jj];

            const float si = frcp(1.f + fexp2(ai));
            const float sf = frcp(1.f + fexp2(af));
            const float tg = fmaf(2.f, frcp(1.f + fexp2(ag)), -1.f);
            const float so = frcp(1.f + fexp2(ao));

            const float cn = fmaf(sf, c[jj], si * tg);
            c[jj] = cn;
            const float th = fmaf(-2.f, frcp(1.f + fexp2(TWOLOG2E * cn)), 1.f);
            hnh[jj] = so * th;
        }

        // ---- own 2 int units ----
#pragma unroll
        for (int jj = 0; jj < 2; ++jj) {
            const int ju = ji0 + jj;
            v2f a0 = wXi[ju]      * xvi;
            v2f a1 = wXi[8 + ju]  * xvi;
            v2f a2 = wXi[16 + ju] * xvi;
            v2f a3 = wXi[24 + ju] * xvi;
            const v2f* w0 = reinterpret_cast<const v2f*>(wWi + ju * 8);
            const v2f* w1 = reinterpret_cast<const v2f*>(wWi + (8 + ju) * 8);
            const v2f* w2 = reinterpret_cast<const v2f*>(wWi + (16 + ju) * 8);
            const v2f* w3 = reinterpret_cast<const v2f*>(wWi + (24 + ju) * 8);
#pragma unroll
            for (int k = 0; k < 4; ++k) {
                const v2f hk = hi2[k];
                a0 += w0[k] * hk;
                a1 += w1[k] * hk;
                a2 += w2[k] * hk;
                a3 += w3[k] * hk;
            }
            const float ai = a0.x + a0.y + bIr[0][jj];
            const float af = a1.x + a1.y + bIr[1][jj];
            const float ag = a2.x + a2.y + bIr[2][jj];
            const float ao = a3.x + a3.y + bIr[3][jj];

            const float si = frcp(1.f + fexp2(ai));
            const float sf = frcp(1.f + fexp2(af));
            const float tg = fmaf(2.f, frcp(1.f + fexp2(ag)), -1.f);
            const float so = frcp(1.f + fexp2(ao));

            const float cn = fmaf(sf, ci[jj], si * tg);
            ci[jj] = cn;
            const float th = fmaf(-2.f, frcp(1.f + fexp2(TWOLOG2E * cn)), 1.f);
            hni[jj] = so * th;
        }

        // ---- publish own h, ONE barrier, read others ----
        const int bf = s & 1;
#pragma unroll
        for (int q = 0; q < 4; ++q) {
            const v2f nh = {hnh[2 * q], hnh[2 * q + 1]};
            h2[wave * 4 + q] = nh;
            hhx[bf][wave * 4 + q][lane] = make_float2(nh.x, nh.y);
        }
        {
            const v2f nh = {hni[0], hni[1]};
            hi2[wave] = nh;
            hix[bf][wave][lane] = make_float2(nh.x, nh.y);
        }
        __syncthreads();
#pragma unroll
        for (int q = 0; q < 16; ++q) {
            if ((q >> 2) != wave) {
                const float2 v = hhx[bf][q][lane];
                h2[q] = (v2f){v.x, v.y};
            }
        }
#pragma unroll
        for (int q = 0; q < 4; ++q) {
            if (q != wave) {
                const float2 v = hix[bf][q][lane];
                hi2[q] = (v2f){v.x, v.y};
            }
        }
        xi = nxi; xh = nxh;
    }

    // ---- projection: every wave holds the full state; wave 0 writes ----
    if (wave == 0) {
        float e0 = b_out[0], e1 = b_out[1];
#pragma unroll
        for (int j = 0; j < 32; ++j) {
            const float hj = (j & 1) ? h2[j >> 1].y : h2[j >> 1].x;
            e0 = fmaf(W_out[j], hj, e0);
            e1 = fmaf(W_out[40 + j], hj, e1);
        }
#pragma unroll
        for (int j = 0; j < 8; ++j) {
            const float hj = (j & 1) ? hi2[j >> 1].y : hi2[j >> 1].x;
            e0 = fmaf(W_out[32 + j], hj, e0);
            e1 = fmaf(W_out[72 + j], hj, e1);
        }
        float2 o; o.x = e0; o.y = e1;
        reinterpret_cast<float2*>(out)[t * 128 + b] = o;
    }
}

extern "C" void kernel_launch(void* const* d_in, const int* in_sizes, int n_in,
                              void* d_out, int out_size, void* d_ws, size_t ws_size,
                              hipStream_t stream) {
    const float* inp     = (const float*)d_in[0];
    const float* Wih_his = (const float*)d_in[1];
    const float* Whh_his = (const float*)d_in[2];
    const float* bih_his = (const float*)d_in[3];
    const float* bhh_his = (const float*)d_in[4];
    const float* Wih_int = (const float*)d_in[5];
    const float* Whh_int = (const float*)d_in[6];
    const float* bih_int = (const float*)d_in[7];
    const float* bhh_int = (const float*)d_in[8];
    const float* W_out   = (const float*)d_in[9];
    const float* b_out   = (const float*)d_in[10];
    float* out = (float*)d_out;
    float* ws  = (float*)d_ws;

    // pre-pass: fold log2e scales + bias merge into ws (4832 floats)
    prep_kernel<<<dim3(19), dim3(256), 0, stream>>>(
        Wih_his, Whh_his, bih_his, bhh_his,
        Wih_int, Whh_int, bih_int, bhh_int, ws);

    // 512 blocks x 256 threads (4 waves): block handles 64 chains of one t;
    // each wave owns 8 his-units + 2 int-units => 2048 waves = 2 per SIMD.
    traj_kernel<<<dim3(512), dim3(256), 0, stream>>>(
        inp, ws, W_out, b_out, out);
}

// Round 7
// 482.918 us; speedup vs baseline: 29.9612x; 1.1579x over previous
//
#include <hip/hip_runtime.h>

// Trajectron sliding-window LSTM embed:
//   inputs [T=256, B=128, N=4, D=2] f32
//   his LSTM H=32 over n=3; int LSTM H=8 over n=0; window 64 ending at t
//   out[t,b,:] = [h_his | h_int] @ W_out.T + b_out   -> [256,128,2] f32
//
// Round-7: R6 structure (chain-per-lane + LDS uniform-address weight
// broadcast + per-step double-buffered h exchange) with two fixes:
//   (a) F=8 unit split: 512-thread blocks, 8 waves, each owns 4 his units
//       + 1 int unit -> 4096 waves = 4 waves/SIMD (2x R6 TLP to hide the
//       lgkm latency of the weight reads, which R6 exposed at 2 waves/SIMD).
//   (b) v_pk_fma_f32 FORCED via inline asm (R6 may have scalarized), bias
//       pre-folded into the accumulator init {bias, 0}.
// Exchange: write own h halves (b32), one barrier, read ALL pairs back
// (16+4 ds_read_b64, lane stride 8B = 2-way bank aliasing = free).
// __launch_bounds__(512,4) caps VGPR at 128 for the 4-waves/SIMD target.

typedef float v2f __attribute__((ext_vector_type(2)));

static __device__ __forceinline__ float fexp2(float x) {
    return __builtin_amdgcn_exp2f(x);
}
static __device__ __forceinline__ float frcp(float x) {
    return __builtin_amdgcn_rcpf(x);
}
static __device__ __forceinline__ void pk_fma(v2f& d, v2f a, v2f b) {
    asm("v_pk_fma_f32 %0, %1, %2, %0" : "+v"(d) : "v"(a), "v"(b));
}
static __device__ __forceinline__ v2f lo2(float4 v) { return (v2f){v.x, v.y}; }
static __device__ __forceinline__ v2f hi2v(float4 v) { return (v2f){v.z, v.w}; }

#define LOG2E    1.442695041f
#define TWOLOG2E 2.885390082f

// ws layout (floats) -- identical to rounds 5/6 (correctness-verified):
//   [0,256)     hisX : 2*r+{0,1} = Wih_his[r][:] * s_r
//   [256,384)   hisB : (bih+bhh)[r] * s_r
//   [384,4480)  hisW : r*32+k = Whh_his[r][k] * s_r
//   [4480,4544) intX
//   [4544,4576) intB
//   [4576,4832) intW : r*8+k
// s_r = -log2e for sigmoid rows (i,f,o), -2*log2e for g rows.
__global__ __launch_bounds__(256) void prep_kernel(
    const float* __restrict__ Wih_his, const float* __restrict__ Whh_his,
    const float* __restrict__ bih_his, const float* __restrict__ bhh_his,
    const float* __restrict__ Wih_int, const float* __restrict__ Whh_int,
    const float* __restrict__ bih_int, const float* __restrict__ bhh_int,
    float* __restrict__ ws)
{
    const int i = blockIdx.x * 256 + threadIdx.x;
    if (i < 256) {                      // hisX
        const int r = i >> 1;
        const float s = (r >= 64 && r < 96) ? -TWOLOG2E : -LOG2E;
        ws[i] = Wih_his[i] * s;
    } else if (i < 384) {               // hisB
        const int r = i - 256;
        const float s = (r >= 64 && r < 96) ? -TWOLOG2E : -LOG2E;
        ws[i] = (bih_his[r] + bhh_his[r]) * s;
    } else if (i < 4480) {              // hisW
        const int e = i - 384, r = e >> 5;
        const float s = (r >= 64 && r < 96) ? -TWOLOG2E : -LOG2E;
        ws[i] = Whh_his[e] * s;
    } else if (i < 4544) {              // intX
        const int e = i - 4480, r = e >> 1;
        const float s = (r >= 16 && r < 24) ? -TWOLOG2E : -LOG2E;
        ws[i] = Wih_int[e] * s;
    } else if (i < 4576) {              // intB
        const int r = i - 4544;
        const float s = (r >= 16 && r < 24) ? -TWOLOG2E : -LOG2E;
        ws[i] = (bih_int[r] + bhh_int[r]) * s;
    } else if (i < 4832) {              // intW
        const int e = i - 4576, r = e >> 3;
        const float s = (r >= 16 && r < 24) ? -TWOLOG2E : -LOG2E;
        ws[i] = Whh_int[e] * s;
    }
}

__global__ __launch_bounds__(512, 4) void traj_kernel(
    const float* __restrict__ inp,     // [256][128][4][2]
    const float* __restrict__ ws,      // preprocessed weights (see prep)
    const float* __restrict__ W_out,   // [2][40]
    const float* __restrict__ b_out,   // [2]
    float* __restrict__ out)           // [256][128][2]
{
    __shared__ __align__(16) float lw[4832];   // broadcast weight copy
    __shared__ float2 hhx[2][16][64];          // his h pairs [buf][pair][chain]
    __shared__ float2 iex[2][4][64];           // int h pairs

    const int tid  = threadIdx.x;
    const int wave = tid >> 6;                  // 0..7
    const int lane = tid & 63;
    const int bid  = blockIdx.x;
    const int t    = bid >> 1;                  // uniform per block
    const int b    = ((bid & 1) << 6) | lane;   // this lane's chain is (t,b)
    const int nsteps = (t >= 63) ? 64 : (t + 1);
    const int tau0   = (t >= 63) ? (t - 63) : 0;

    // ---- stage weights global -> LDS (once) ----
    {
        const float4* src = reinterpret_cast<const float4*>(ws);
        float4*       dst = reinterpret_cast<float4*>(lw);
        for (int idx = tid; idx < 1208; idx += 512) dst[idx] = src[idx];
    }
    __syncthreads();

    const v2f*   wX  = reinterpret_cast<const v2f*>(lw);          // [128]
    const float* wB  = lw + 256;                                  // [128]
    const float* wW  = lw + 384;                                  // [128][32]
    const v2f*   wXi = reinterpret_cast<const v2f*>(lw + 4480);   // [32]
    const float* wBi = lw + 4544;                                 // [32]
    const float* wWi = lw + 4576;                                 // [32][8]

    const int ju0 = wave * 4;    // own his units [ju0, ju0+4); own int unit = wave

    v2f h2[16], hi2[4];
    float c[4], ci;
#pragma unroll
    for (int m = 0; m < 16; ++m) h2[m] = (v2f){0.f, 0.f};
#pragma unroll
    for (int m = 0; m < 4; ++m) hi2[m] = (v2f){0.f, 0.f};
    c[0] = c[1] = c[2] = c[3] = 0.f;
    ci = 0.f;

    const float* xq = inp + tau0 * 1024 + b * 8;
    float2 xi = *reinterpret_cast<const float2*>(xq);       // n=0
    float2 xh = *reinterpret_cast<const float2*>(xq + 6);   // n=3
    xq += 1024;

#pragma unroll 1
    for (int s = 0; s < nsteps; ++s) {
        float2 nxi = {0.f, 0.f}, nxh = {0.f, 0.f};
        if (s + 1 < nsteps) {                               // uniform branch
            nxi = *reinterpret_cast<const float2*>(xq);
            nxh = *reinterpret_cast<const float2*>(xq + 6);
        }
        xq += 1024;
        const v2f xvh = {xh.x, xh.y};
        const v2f xvi = {xi.x, xi.y};
        const int bf = s & 1;

        // ---- own 4 his units ----
#pragma unroll
        for (int jj = 0; jj < 4; ++jj) {
            const int ju = ju0 + jj;
            const float4* w0 = reinterpret_cast<const float4*>(wW + ju * 32);
            const float4* w1 = reinterpret_cast<const float4*>(wW + (32 + ju) * 32);
            const float4* w2 = reinterpret_cast<const float4*>(wW + (64 + ju) * 32);
            const float4* w3 = reinterpret_cast<const float4*>(wW + (96 + ju) * 32);

            v2f a0 = {wB[ju], 0.f};          // bias folded into acc.x
            v2f a1 = {wB[32 + ju], 0.f};
            v2f a2 = {wB[64 + ju], 0.f};
            v2f a3 = {wB[96 + ju], 0.f};
            pk_fma(a0, wX[ju],      xvh);
            pk_fma(a1, wX[32 + ju], xvh);
            pk_fma(a2, wX[64 + ju], xvh);
            pk_fma(a3, wX[96 + ju], xvh);
#pragma unroll
            for (int k = 0; k < 8; ++k) {
                const float4 W0 = w0[k], W1 = w1[k], W2 = w2[k], W3 = w3[k];
                const v2f hA = h2[2 * k], hB = h2[2 * k + 1];
                pk_fma(a0, lo2(W0), hA); pk_fma(a0, hi2v(W0), hB);
                pk_fma(a1, lo2(W1), hA); pk_fma(a1, hi2v(W1), hB);
                pk_fma(a2, lo2(W2), hA); pk_fma(a2, hi2v(W2), hB);
                pk_fma(a3, lo2(W3), hA); pk_fma(a3, hi2v(W3), hB);
            }
            const float ai = a0.x + a0.y;
            const float af = a1.x + a1.y;
            const float ag = a2.x + a2.y;
            const float ao = a3.x + a3.y;

            const float si = frcp(1.f + fexp2(ai));
            const float sf = frcp(1.f + fexp2(af));
            const float tg = fmaf(2.f, frcp(1.f + fexp2(ag)), -1.f);
            const float so = frcp(1.f + fexp2(ao));

            const float cn = fmaf(sf, c[jj], si * tg);
            c[jj] = cn;
            const float th = fmaf(-2.f, frcp(1.f + fexp2(TWOLOG2E * cn)), 1.f);
            const float hj = so * th;
            // publish own half directly (pair ju>>1, half ju&1)
            reinterpret_cast<float*>(&hhx[bf][ju >> 1][lane])[ju & 1] = hj;
        }

        // ---- own 1 int unit (= wave) ----
        {
            const float4* wb = reinterpret_cast<const float4*>(wWi + wave * 8);
            v2f a0 = {wBi[wave], 0.f};
            v2f a1 = {wBi[8 + wave], 0.f};
            v2f a2 = {wBi[16 + wave], 0.f};
            v2f a3 = {wBi[24 + wave], 0.f};
            pk_fma(a0, wXi[wave],      xvi);
            pk_fma(a1, wXi[8 + wave],  xvi);
            pk_fma(a2, wXi[16 + wave], xvi);
            pk_fma(a3, wXi[24 + wave], xvi);
#pragma unroll
            for (int k = 0; k < 2; ++k) {
                const float4 W0 = wb[k], W1 = wb[16 + k];
                const float4 W2 = wb[32 + k], W3 = wb[48 + k];
                const v2f hA = hi2[2 * k], hB = hi2[2 * k + 1];
                pk_fma(a0, lo2(W0), hA); pk_fma(a0, hi2v(W0), hB);
                pk_fma(a1, lo2(W1), hA); pk_fma(a1, hi2v(W1), hB);
                pk_fma(a2, lo2(W2), hA); pk_fma(a2, hi2v(W2), hB);
                pk_fma(a3, lo2(W3), hA); pk_fma(a3, hi2v(W3), hB);
            }
            const float ai = a0.x + a0.y;
            const float af = a1.x + a1.y;
            const float ag = a2.x + a2.y;
            const float ao = a3.x + a3.y;

            const float si = frcp(1.f + fexp2(ai));
            const float sf = frcp(1.f + fexp2(af));
            const float tg = fmaf(2.f, frcp(1.f + fexp2(ag)), -1.f);
            const float so = frcp(1.f + fexp2(ao));

            const float cn = fmaf(sf, ci, si * tg);
            ci = cn;
            const float th = fmaf(-2.f, frcp(1.f + fexp2(TWOLOG2E * cn)), 1.f);
            const float hj = so * th;
            reinterpret_cast<float*>(&iex[bf][wave >> 1][lane])[wave & 1] = hj;
        }

        __syncthreads();

        // ---- read ALL pairs back (own halves just written are current) ----
#pragma unroll
        for (int q = 0; q < 16; ++q) {
            const float2 v = hhx[bf][q][lane];
            h2[q] = (v2f){v.x, v.y};
        }
#pragma unroll
        for (int q = 0; q < 4; ++q) {
            const float2 v = iex[bf][q][lane];
            hi2[q] = (v2f){v.x, v.y};
        }
        xi = nxi; xh = nxh;
    }

    // ---- projection: wave 0 holds the full state mirrors ----
    if (wave == 0) {
        float e0 = b_out[0], e1 = b_out[1];
#pragma unroll
        for (int j = 0; j < 32; ++j) {
            const float hj = (j & 1) ? h2[j >> 1].y : h2[j >> 1].x;
            e0 = fmaf(W_out[j], hj, e0);
            e1 = fmaf(W_out[40 + j], hj, e1);
        }
#pragma unroll
        for (int j = 0; j < 8; ++j) {
            const float hj = (j & 1) ? hi2[j >> 1].y : hi2[j >> 1].x;
            e0 = fmaf(W_out[32 + j], hj, e0);
            e1 = fmaf(W_out[72 + j], hj, e1);
        }
        float2 o; o.x = e0; o.y = e1;
        reinterpret_cast<float2*>(out)[t * 128 + b] = o;
    }
}

extern "C" void kernel_launch(void* const* d_in, const int* in_sizes, int n_in,
                              void* d_out, int out_size, void* d_ws, size_t ws_size,
                              hipStream_t stream) {
    const float* inp     = (const float*)d_in[0];
    const float* Wih_his = (const float*)d_in[1];
    const float* Whh_his = (const float*)d_in[2];
    const float* bih_his = (const float*)d_in[3];
    const float* bhh_his = (const float*)d_in[4];
    const float* Wih_int = (const float*)d_in[5];
    const float* Whh_int = (const float*)d_in[6];
    const float* bih_int = (const float*)d_in[7];
    const float* bhh_int = (const float*)d_in[8];
    const float* W_out   = (const float*)d_in[9];
    const float* b_out   = (const float*)d_in[10];
    float* out = (float*)d_out;
    float* ws  = (float*)d_ws;

    // pre-pass: fold log2e scales + bias merge into ws (4832 floats)
    prep_kernel<<<dim3(19), dim3(256), 0, stream>>>(
        Wih_his, Whh_his, bih_his, bhh_his,
        Wih_int, Whh_int, bih_int, bhh_int, ws);

    // 512 blocks x 512 threads (8 waves): block = 64 chains of one t;
    // each wave owns 4 his units + 1 int unit => 4096 waves = 4 per SIMD.
    traj_kernel<<<dim3(512), dim3(512), 0, stream>>>(
        inp, ws, W_out, b_out, out);
}

// Round 8
// 452.080 us; speedup vs baseline: 32.0049x; 1.0682x over previous
//
#include <hip/hip_runtime.h>

// Trajectron sliding-window LSTM embed:
//   inputs [T=256, B=128, N=4, D=2] f32
//   his LSTM H=32 over n=3; int LSTM H=8 over n=0; window 64 ending at t
//   out[t,b,:] = [h_his | h_int] @ W_out.T + b_out   -> [256,128,2] f32
//
// Round-8: unit-per-lane, weights VGPR-resident. R7 was LDS-return-bandwidth
// bound: chain-per-lane re-reads the whole 16KB weight matrix per chain-step
// (broadcast dedupes conflicts, NOT return bytes: uniform b128 = 1KB/wave).
// Unit-per-lane replicates only h: 4KB/chain-step, 4x less. Lane (c,j) owns
// unit j of chain c (2 chains/wave); 4 gate rows = 128 floats in VGPRs,
// loaded once and pinned behind a memory-clobber asm (cannot sink into the
// loop). Int LSTM on the same lanes (unit j&7, writers j<8). No barriers in
// the loop: wave-private double-buffered h + R2-verified wave fence.

typedef float v2f __attribute__((ext_vector_type(2)));

static __device__ __forceinline__ float fexp2(float x) {
    return __builtin_amdgcn_exp2f(x);
}
static __device__ __forceinline__ float frcp(float x) {
    return __builtin_amdgcn_rcpf(x);
}
static __device__ __forceinline__ void pk_fma(v2f& d, v2f a, v2f b) {
    asm("v_pk_fma_f32 %0, %1, %2, %0" : "+v"(d) : "v"(a), "v"(b));
}
static __device__ __forceinline__ v2f lo2(float4 v) { return (v2f){v.x, v.y}; }
static __device__ __forceinline__ v2f hi2v(float4 v) { return (v2f){v.z, v.w}; }

#define LOG2E    1.442695041f
#define TWOLOG2E 2.885390082f

// ws layout (floats) -- identical to rounds 5-7 (correctness-verified):
//   [0,256)     hisX : 2*r+{0,1} = Wih_his[r][:] * s_r
//   [256,384)   hisB : (bih+bhh)[r] * s_r
//   [384,4480)  hisW : r*32+k = Whh_his[r][k] * s_r
//   [4480,4544) intX
//   [4544,4576) intB
//   [4576,4832) intW : r*8+k
// s_r = -log2e for sigmoid rows (i,f,o), -2*log2e for g rows.
__global__ __launch_bounds__(256) void prep_kernel(
    const float* __restrict__ Wih_his, const float* __restrict__ Whh_his,
    const float* __restrict__ bih_his, const float* __restrict__ bhh_his,
    const float* __restrict__ Wih_int, const float* __restrict__ Whh_int,
    const float* __restrict__ bih_int, const float* __restrict__ bhh_int,
    float* __restrict__ ws)
{
    const int i = blockIdx.x * 256 + threadIdx.x;
    if (i < 256) {                      // hisX
        const int r = i >> 1;
        const float s = (r >= 64 && r < 96) ? -TWOLOG2E : -LOG2E;
        ws[i] = Wih_his[i] * s;
    } else if (i < 384) {               // hisB
        const int r = i - 256;
        const float s = (r >= 64 && r < 96) ? -TWOLOG2E : -LOG2E;
        ws[i] = (bih_his[r] + bhh_his[r]) * s;
    } else if (i < 4480) {              // hisW
        const int e = i - 384, r = e >> 5;
        const float s = (r >= 64 && r < 96) ? -TWOLOG2E : -LOG2E;
        ws[i] = Whh_his[e] * s;
    } else if (i < 4544) {              // intX
        const int e = i - 4480, r = e >> 1;
        const float s = (r >= 16 && r < 24) ? -TWOLOG2E : -LOG2E;
        ws[i] = Wih_int[e] * s;
    } else if (i < 4576) {              // intB
        const int r = i - 4544;
        const float s = (r >= 16 && r < 24) ? -TWOLOG2E : -LOG2E;
        ws[i] = (bih_int[r] + bhh_int[r]) * s;
    } else if (i < 4832) {              // intW
        const int e = i - 4576, r = e >> 3;
        const float s = (r >= 16 && r < 24) ? -TWOLOG2E : -LOG2E;
        ws[i] = Whh_int[e] * s;
    }
}

__global__ __launch_bounds__(256, 2) void traj_kernel(
    const float* __restrict__ inp,     // [256][128][4][2]
    const float* __restrict__ ws,      // preprocessed weights (see prep)
    const float* __restrict__ W_out,   // [2][40]
    const float* __restrict__ b_out,   // [2]
    float* __restrict__ out)           // [256][128][2]
{
    __shared__ __align__(16) float lw[4832];         // staged weights
    __shared__ __align__(16) float hb[4][2][2][32];  // [wave][buf][chain][unit]
    __shared__ __align__(16) float ib[4][2][2][8];   // int h

    const int tid  = threadIdx.x;
    const int wave = tid >> 6;
    const int lane = tid & 63;
    const int W    = blockIdx.x * 4 + wave;     // wave id: 2 chains {2W, 2W+1}
    const int t    = W >> 6;                    // uniform per wave (and block)
    const int c    = lane >> 5;                 // chain half
    const int j    = lane & 31;                 // his unit
    const int jj   = j & 7;                     // int unit (redundant x4)
    const int b    = ((W & 63) << 1) | c;
    const int nsteps = (t >= 63) ? 64 : (t + 1);
    const int tau0   = (t >= 63) ? (t - 63) : 0;

    // ---- stage weights global -> LDS (coalesced, once) ----
    {
        const float4* src = reinterpret_cast<const float4*>(ws);
        float4*       dst = reinterpret_cast<float4*>(lw);
        for (int i = tid; i < 1208; i += 256) dst[i] = src[i];
    }
    __syncthreads();

    // ---- own weights LDS -> VGPRs, ONCE; pinned behind a memory barrier ----
    float4 wh[4][8];          // his rows g*32+j, k-packed     (128 VGPRs)
    float4 wi[4][2];          // int rows g*8+jj               (32 VGPRs)
    float  bh[4], bi[4];
    v2f    wxh[4], wxi[4];
    {
        const float* wWh = lw + 384;
        const float* wWi = lw + 4576;
#pragma unroll
        for (int g = 0; g < 4; ++g) {
            const float4* row = reinterpret_cast<const float4*>(wWh + (g * 32 + j) * 32);
#pragma unroll
            for (int q = 0; q < 8; ++q) wh[g][q] = row[q];
            const float4* rowi = reinterpret_cast<const float4*>(wWi + (g * 8 + jj) * 8);
            wi[g][0] = rowi[0];
            wi[g][1] = rowi[1];
            bh[g]  = lw[256 + g * 32 + j];
            bi[g]  = lw[4544 + g * 8 + jj];
            wxh[g] = reinterpret_cast<const v2f*>(lw)[g * 32 + j];
            wxi[g] = reinterpret_cast<const v2f*>(lw + 4480)[g * 8 + jj];
        }
    }
    // loads above may not sink past this (asm may write memory) -> values
    // must stay in registers (or visibly spill to scratch) for the loop.
    asm volatile("" ::: "memory");

    // ---- init h buffers + cell state ----
    hb[wave][0][c][j] = 0.f;
    if (j < 8) ib[wave][0][c][j] = 0.f;
    float cc = 0.f, cci = 0.f;
    float hFin = 0.f, hiFin = 0.f;

    const float* xc = inp + tau0 * 1024 + b * 8;
    float2 xh2 = *reinterpret_cast<const float2*>(xc + 6);   // n=3
    float2 xi2 = *reinterpret_cast<const float2*>(xc);       // n=0
    xc += 1024;

#pragma unroll 1
    for (int s = 0; s < nsteps; ++s) {
        // wave-local fence: prior h writes visible (R2-verified pattern)
        __builtin_amdgcn_wave_barrier();
        asm volatile("s_waitcnt lgkmcnt(0)" ::: "memory");
        __builtin_amdgcn_wave_barrier();

        const int rb = s & 1, wb = rb ^ 1;

        // read chain-c h (uniform per half-wave: broadcast, conflict-free)
        float4 hv[8];
        {
            const float4* hp = reinterpret_cast<const float4*>(&hb[wave][rb][c][0]);
#pragma unroll
            for (int q = 0; q < 8; ++q) hv[q] = hp[q];
        }
        float4 iv0, iv1;
        {
            const float4* ip = reinterpret_cast<const float4*>(&ib[wave][rb][c][0]);
            iv0 = ip[0]; iv1 = ip[1];
        }

        float2 nxh = {0.f, 0.f}, nxi = {0.f, 0.f};
        if (s + 1 < nsteps) {                     // wave-uniform branch
            nxh = *reinterpret_cast<const float2*>(xc + 6);
            nxi = *reinterpret_cast<const float2*>(xc);
        }
        xc += 1024;

        const v2f xvh = {xh2.x, xh2.y};
        const v2f xvi = {xi2.x, xi2.y};

        // ---- his: 4 gate dot products, all operands in VGPRs ----
        float a[4];
#pragma unroll
        for (int g = 0; g < 4; ++g) {
            v2f acc = {bh[g], 0.f};
            pk_fma(acc, wxh[g], xvh);
#pragma unroll
            for (int q = 0; q < 8; ++q) {
                pk_fma(acc, lo2(wh[g][q]), lo2(hv[q]));
                pk_fma(acc, hi2v(wh[g][q]), hi2v(hv[q]));
            }
            a[g] = acc.x + acc.y;
        }
        const float si = frcp(1.f + fexp2(a[0]));
        const float sf = frcp(1.f + fexp2(a[1]));
        const float tg = fmaf(2.f, frcp(1.f + fexp2(a[2])), -1.f);
        const float so = frcp(1.f + fexp2(a[3]));
        cc = fmaf(sf, cc, si * tg);
        hFin = so * fmaf(-2.f, frcp(1.f + fexp2(TWOLOG2E * cc)), 1.f);
        hb[wave][wb][c][j] = hFin;     // 64 unique slots: conflict-free b32

        // ---- int: unit jj (computed redundantly on 4 j-groups) ----
        float ai[4];
#pragma unroll
        for (int g = 0; g < 4; ++g) {
            v2f acc = {bi[g], 0.f};
            pk_fma(acc, wxi[g], xvi);
            pk_fma(acc, lo2(wi[g][0]), lo2(iv0));
            pk_fma(acc, hi2v(wi[g][0]), hi2v(iv0));
            pk_fma(acc, lo2(wi[g][1]), lo2(iv1));
            pk_fma(acc, hi2v(wi[g][1]), hi2v(iv1));
            ai[g] = acc.x + acc.y;
        }
        const float sii = frcp(1.f + fexp2(ai[0]));
        const float sfi = frcp(1.f + fexp2(ai[1]));
        const float tgi = fmaf(2.f, frcp(1.f + fexp2(ai[2])), -1.f);
        const float soi = frcp(1.f + fexp2(ai[3]));
        cci = fmaf(sfi, cci, sii * tgi);
        hiFin = soi * fmaf(-2.f, frcp(1.f + fexp2(TWOLOG2E * cci)), 1.f);
        if (j < 8) ib[wave][wb][c][j] = hiFin;

        xh2 = nxh; xi2 = nxi;
    }

    // ---- projection: lane contributes its own unit(s); reduce over 32 ----
    float e0 = W_out[j] * hFin;
    float e1 = W_out[40 + j] * hFin;
    if (j < 8) {
        e0 = fmaf(W_out[32 + j], hiFin, e0);
        e1 = fmaf(W_out[72 + j], hiFin, e1);
    }
#pragma unroll
    for (int m = 16; m >= 1; m >>= 1) {
        e0 += __shfl_xor(e0, m);
        e1 += __shfl_xor(e1, m);
    }
    if (j == 0) {
        float2 o;
        o.x = e0 + b_out[0];
        o.y = e1 + b_out[1];
        reinterpret_cast<float2*>(out)[t * 128 + b] = o;
    }
}

extern "C" void kernel_launch(void* const* d_in, const int* in_sizes, int n_in,
                              void* d_out, int out_size, void* d_ws, size_t ws_size,
                              hipStream_t stream) {
    const float* inp     = (const float*)d_in[0];
    const float* Wih_his = (const float*)d_in[1];
    const float* Whh_his = (const float*)d_in[2];
    const float* bih_his = (const float*)d_in[3];
    const float* bhh_his = (const float*)d_in[4];
    const float* Wih_int = (const float*)d_in[5];
    const float* Whh_int = (const float*)d_in[6];
    const float* bih_int = (const float*)d_in[7];
    const float* bhh_int = (const float*)d_in[8];
    const float* W_out   = (const float*)d_in[9];
    const float* b_out   = (const float*)d_in[10];
    float* out = (float*)d_out;
    float* ws  = (float*)d_ws;

    // pre-pass: fold log2e scales + bias merge into ws (4832 floats)
    prep_kernel<<<dim3(19), dim3(256), 0, stream>>>(
        Wih_his, Whh_his, bih_his, bhh_his,
        Wih_int, Whh_int, bih_int, bhh_int, ws);

    // 4096 blocks x 256 threads (4 waves); wave = 2 chains (unit-per-lane).
    traj_kernel<<<dim3(4096), dim3(256), 0, stream>>>(
        inp, ws, W_out, b_out, out);
}